// Round 1
// baseline (2163.108 us; speedup 1.0000x reference)
//
#include <hip/hip_runtime.h>
#include <hip/hip_bf16.h>
#include <math.h>

// ---------------------------------------------------------------------------
// S2ConvNetModified pipeline, fp32 baseline (g intermediate in bf16)
//
// Sizes:
//   x        [32,1,96,96]      w1 [1,20,24]       w2 [20,40,168]
//   Yk1      [24,121]          Dk2 [168,286]      from_s2 [121,9216]
//   D1_to    [32000,1771]      F1_from [286,32000]
//   D2_to    [6912,286]        F2_from [1,6912]
//   out      [32,40,1]
// ---------------------------------------------------------------------------

#define B_      32
#define F1_     20
#define F2_     40
#define NC1     1771
#define NG1     32000
#define NC2     286
#define NG2     6912
#define SQRT2_  1.41421356237309515f
#define RS24    0.20412414523193154f   // 1/sqrt(24)
#define RS168   0.07715167498104595f   // 1/sqrt(168)

__device__ __forceinline__ float wave_reduce(float v) {
#pragma unroll
  for (int o = 32; o > 0; o >>= 1) v += __shfl_down(v, o, 64);
  return v;
}

// c[b,ch] = sum_g x_t[b,g] * from_s2[ch,g],  x_t flat index g = j*96 + i,
// x[b,0,i,j] at b*9216 + i*96 + j
__global__ void k_c(const float* __restrict__ x, const float* __restrict__ fs,
                    float* __restrict__ c) {
  const int ch = blockIdx.x, b = blockIdx.y, tid = threadIdx.x;
  const float* xb = x + b * 9216;
  const float* fr = fs + ch * 9216;
  float s = 0.f;
  for (int g = tid; g < 9216; g += 256) {
    s += xb[(g % 96) * 96 + (g / 96)] * fr[g];
  }
  s = wave_reduce(s);
  __shared__ float red[4];
  if ((tid & 63) == 0) red[tid >> 6] = s;
  __syncthreads();
  if (tid == 0) c[b * 121 + ch] = red[0] + red[1] + red[2] + red[3];
}

// psi1[j,i] = (1/sqrt(24)) * sum_n Yk1[n,i] * w1[j,n]
__global__ void k_psi1(const float* __restrict__ Yk1, const float* __restrict__ w1,
                       float* __restrict__ psi1) {
  const int j = blockIdx.x, i = threadIdx.x;
  __shared__ float wsm[24];
  if (i < 24) wsm[i] = w1[j * 24 + i];
  __syncthreads();
  if (i < 121) {
    float s = 0.f;
#pragma unroll
    for (int n = 0; n < 24; ++n) s += Yk1[n * 121 + i] * wsm[n];
    psi1[j * 121 + i] = s * RS24;
  }
}

// h[b,j, off_l + n*k + m] = c[b, l*l+m] * psi1[j, l*l+n]
__global__ void k_h(const float* __restrict__ c, const float* __restrict__ psi1,
                    float* __restrict__ h) {
  const int j = blockIdx.x, b = blockIdx.y, tid = threadIdx.x;
  __shared__ float cs[121], ps[121];
  if (tid < 121) { cs[tid] = c[b * 121 + tid]; ps[tid] = psi1[j * 121 + tid]; }
  __syncthreads();
  for (int idx = tid; idx < NC1; idx += 256) {
    int off = 0, l = 0, k = 1;
    while (idx >= off + k * k) { off += k * k; ++l; k += 2; }
    const int r = idx - off, n = r / k, m = r % k;
    h[(b * F1_ + j) * NC1 + idx] = cs[l * l + m] * ps[l * l + n];
  }
}

// GEMM1: g[m,n] = sqrt(2)*relu( sum_k h[m,k] * D1_to[n,k] ),  store bf16
// M=640, N=32000, K=1771
__launch_bounds__(256)
__global__ void k_gemm1(const float* __restrict__ A, const float* __restrict__ Bm,
                        __hip_bfloat16* __restrict__ C) {
  __shared__ float As[16][68];
  __shared__ float Bs[16][68];
  const int m0 = blockIdx.x * 64;   // 10 m-tiles (x fastest -> B-tile reuse in L2)
  const int n0 = blockIdx.y * 64;   // 500 n-tiles
  const int tid = threadIdx.x, tx = tid & 15, ty = tid >> 4;
  float acc[4][4] = {};
  const int K = NC1;
  for (int k0 = 0; k0 < K; k0 += 16) {
#pragma unroll
    for (int i = 0; i < 4; ++i) {
      const int e = tid + 256 * i, row = e >> 4, col = e & 15, kk = k0 + col;
      As[col][row] = (kk < K) ? A[(m0 + row) * K + kk] : 0.f;
      Bs[col][row] = (kk < K) ? Bm[(n0 + row) * K + kk] : 0.f;
    }
    __syncthreads();
#pragma unroll
    for (int kk = 0; kk < 16; ++kk) {
      const float4 av = *(const float4*)&As[kk][ty * 4];
      const float4 bv = *(const float4*)&Bs[kk][tx * 4];
      const float a0[4] = {av.x, av.y, av.z, av.w};
      const float b0[4] = {bv.x, bv.y, bv.z, bv.w};
#pragma unroll
      for (int i = 0; i < 4; ++i)
#pragma unroll
        for (int j = 0; j < 4; ++j) acc[i][j] += a0[i] * b0[j];
    }
    __syncthreads();
  }
#pragma unroll
  for (int i = 0; i < 4; ++i) {
    const int m = m0 + ty * 4 + i;
#pragma unroll
    for (int j = 0; j < 4; ++j) {
      const int n = n0 + tx * 4 + j;
      float v = acc[i][j];
      v = (v > 0.f) ? v * SQRT2_ : 0.f;
      C[m * NG1 + n] = __float2bfloat16(v);
    }
  }
}

// GEMM2 (split-K=16, atomic): h2[m,n] += sum_k g[m,k]*F1_from[n,k]
// M=640, N=286, K=32000
__launch_bounds__(256)
__global__ void k_gemm2(const __hip_bfloat16* __restrict__ A, const float* __restrict__ Bm,
                        float* __restrict__ C) {
  __shared__ float As[16][68];
  __shared__ float Bs[16][68];
  const int n0 = blockIdx.x * 64;          // 5 tiles (last partial)
  const int m0 = blockIdx.y * 64;          // 10 tiles
  const int ks = blockIdx.z * 2000;        // 16 K-chunks
  const int tid = threadIdx.x, tx = tid & 15, ty = tid >> 4;
  float acc[4][4] = {};
  for (int k0 = ks; k0 < ks + 2000; k0 += 16) {
#pragma unroll
    for (int i = 0; i < 4; ++i) {
      const int e = tid + 256 * i, row = e >> 4, col = e & 15, kk = k0 + col;
      As[col][row] = __bfloat162float(A[(m0 + row) * NG1 + kk]);
      const int n = n0 + row;
      Bs[col][row] = (n < NC2) ? Bm[n * NG1 + kk] : 0.f;
    }
    __syncthreads();
#pragma unroll
    for (int kk = 0; kk < 16; ++kk) {
      const float4 av = *(const float4*)&As[kk][ty * 4];
      const float4 bv = *(const float4*)&Bs[kk][tx * 4];
      const float a0[4] = {av.x, av.y, av.z, av.w};
      const float b0[4] = {bv.x, bv.y, bv.z, bv.w};
#pragma unroll
      for (int i = 0; i < 4; ++i)
#pragma unroll
        for (int j = 0; j < 4; ++j) acc[i][j] += a0[i] * b0[j];
    }
    __syncthreads();
  }
#pragma unroll
  for (int i = 0; i < 4; ++i) {
    const int m = m0 + ty * 4 + i;
#pragma unroll
    for (int j = 0; j < 4; ++j) {
      const int n = n0 + tx * 4 + j;
      if (n < NC2) atomicAdd(&C[m * NC2 + n], acc[i][j]);
    }
  }
}

// psi2[i,j,c] = (1/sqrt(168)) * sum_n Dk2[n,c] * w2[i,j,n]
__global__ void k_psi2(const float* __restrict__ Dk2, const float* __restrict__ w2,
                       float* __restrict__ psi2) {
  const int blk = blockIdx.x, tid = threadIdx.x;   // blk = i*40+j
  __shared__ float w2s[168];
  if (tid < 168) w2s[tid] = w2[blk * 168 + tid];
  __syncthreads();
  for (int cc = tid; cc < NC2; cc += 256) {
    float s = 0.f;
    for (int n = 0; n < 168; ++n) s += Dk2[n * NC2 + cc] * w2s[n];
    psi2[blk * NC2 + cc] = s * RS168;
  }
}

// per-l SO(3)xSO(3) conv:
// h3[b,j, off + v*k + m] = (1/sqrt(20k)) * sum_{i,u} h2[b,i,off+u*k+m]*psi2[i,j,off+u*k+v]
__global__ void k_step7(const float* __restrict__ h2, const float* __restrict__ psi2,
                        float* __restrict__ h3) {
  const int j = blockIdx.x, b = blockIdx.y, tid = threadIdx.x;
  __shared__ float sh[20 * 286];
  __shared__ float sp[20 * 286];
  for (int e = tid; e < 20 * 286; e += 256) {
    const int i = e / 286, cc = e % 286;
    sh[e] = h2[(b * F1_ + i) * NC2 + cc];
    sp[e] = psi2[(i * F2_ + j) * NC2 + cc];
  }
  __syncthreads();
  for (int cidx = tid; cidx < NC2; cidx += 256) {
    int off = 0, l = 0, k = 1;
    while (cidx >= off + k * k) { off += k * k; ++l; k += 2; }
    const int r = cidx - off, v = r / k, m = r % k;
    float acc = 0.f;
    for (int i = 0; i < 20; ++i) {
      const float* hb = &sh[i * 286 + off];
      const float* pb = &sp[i * 286 + off];
      for (int u = 0; u < k; ++u) acc += hb[u * k + m] * pb[u * k + v];
    }
    h3[(b * F2_ + j) * NC2 + cidx] = acc * rsqrtf(20.f * (float)k);
  }
}

// GEMM3 fused with final activation+reduction:
// out[m] += sqrt(2) * sum_n relu( sum_k h3[m,k]*D2_to[n,k] ) * F2_from[n]
// M=1280, N=6912, K=286
__launch_bounds__(256)
__global__ void k_gemm3(const float* __restrict__ A, const float* __restrict__ Bm,
                        const float* __restrict__ w, float* __restrict__ out) {
  __shared__ float As[16][68];
  __shared__ float Bs[16][68];
  __shared__ float red[64][17];
  const int m0 = blockIdx.x * 64;   // 20 tiles
  const int n0 = blockIdx.y * 64;   // 108 tiles
  const int tid = threadIdx.x, tx = tid & 15, ty = tid >> 4;
  float acc[4][4] = {};
  const int K = NC2;
  for (int k0 = 0; k0 < K; k0 += 16) {
#pragma unroll
    for (int i = 0; i < 4; ++i) {
      const int e = tid + 256 * i, row = e >> 4, col = e & 15, kk = k0 + col;
      As[col][row] = (kk < K) ? A[(m0 + row) * K + kk] : 0.f;
      Bs[col][row] = (kk < K) ? Bm[(n0 + row) * K + kk] : 0.f;
    }
    __syncthreads();
#pragma unroll
    for (int kk = 0; kk < 16; ++kk) {
      const float4 av = *(const float4*)&As[kk][ty * 4];
      const float4 bv = *(const float4*)&Bs[kk][tx * 4];
      const float a0[4] = {av.x, av.y, av.z, av.w};
      const float b0[4] = {bv.x, bv.y, bv.z, bv.w};
#pragma unroll
      for (int i = 0; i < 4; ++i)
#pragma unroll
        for (int j = 0; j < 4; ++j) acc[i][j] += a0[i] * b0[j];
    }
    __syncthreads();
  }
#pragma unroll
  for (int i = 0; i < 4; ++i) {
    float t = 0.f;
#pragma unroll
    for (int j = 0; j < 4; ++j) {
      float v = acc[i][j];
      v = (v > 0.f) ? v : 0.f;
      t += v * w[n0 + tx * 4 + j];
    }
    red[ty * 4 + i][tx] = t;
  }
  __syncthreads();
  if (tid < 64) {
    float t = 0.f;
#pragma unroll
    for (int q = 0; q < 16; ++q) t += red[tid][q];
    atomicAdd(&out[m0 + tid], t * SQRT2_);
  }
}

extern "C" void kernel_launch(void* const* d_in, const int* in_sizes, int n_in,
                              void* d_out, int out_size, void* d_ws, size_t ws_size,
                              hipStream_t stream) {
  const float* x       = (const float*)d_in[0];
  const float* w1      = (const float*)d_in[1];
  const float* w2      = (const float*)d_in[2];
  const float* Yk1     = (const float*)d_in[3];
  const float* Dk2     = (const float*)d_in[4];
  const float* from_s2 = (const float*)d_in[5];
  const float* D1_to   = (const float*)d_in[6];
  const float* F1_from = (const float*)d_in[7];
  const float* D2_to   = (const float*)d_in[8];
  const float* F2_from = (const float*)d_in[9];
  float* out = (float*)d_out;

  float* ws = (float*)d_ws;
  float* c    = ws + 0;          //   3872
  float* psi1 = ws + 3872;       //   2420
  float* h    = ws + 6292;       // 640*1771   = 1133440
  float* h2   = ws + 1139732;    // 640*286    = 183040
  float* psi2 = ws + 1322772;    // 800*286    = 228800
  float* h3   = ws + 1551572;    // 1280*286   = 366080
  __hip_bfloat16* g = (__hip_bfloat16*)(ws + 1917652);  // 640*32000 bf16 = 40.96 MB
  // total workspace: ~48.6 MB

  k_c   <<<dim3(121, 32), 256, 0, stream>>>(x, from_s2, c);
  k_psi1<<<dim3(20),      128, 0, stream>>>(Yk1, w1, psi1);
  k_h   <<<dim3(20, 32),  256, 0, stream>>>(c, psi1, h);

  k_gemm1<<<dim3(10, 500), 256, 0, stream>>>(h, D1_to, g);

  hipMemsetAsync(h2, 0, (size_t)640 * 286 * sizeof(float), stream);
  k_gemm2<<<dim3(5, 10, 16), 256, 0, stream>>>(g, F1_from, h2);

  k_psi2 <<<dim3(800),    256, 0, stream>>>(Dk2, w2, psi2);
  k_step7<<<dim3(40, 32), 256, 0, stream>>>(h2, psi2, h3);

  hipMemsetAsync(out, 0, (size_t)1280 * sizeof(float), stream);
  k_gemm3<<<dim3(20, 108), 256, 0, stream>>>(h3, D2_to, F2_from, out);
}

// Round 2
// 1238.866 us; speedup vs baseline: 1.7460x; 1.7460x over previous
//
#include <hip/hip_runtime.h>
#include <hip/hip_bf16.h>
#include <math.h>

// ---------------------------------------------------------------------------
// S2ConvNetModified pipeline.
// Round 2: GEMM1 + GEMM2 on bf16 MFMA (16x16x32), on-the-fly fp32->bf16 B
// staging, A staged via global_load_lds width=16.
// ---------------------------------------------------------------------------

#define B_      32
#define F1_     20
#define F2_     40
#define NC1     1771
#define K1P     1792          // NC1 padded to multiple of 32
#define NG1     32000
#define NC2     286
#define NG2     6912
#define SQRT2_  1.41421356237309515f
#define RS24    0.20412414523193154f   // 1/sqrt(24)
#define RS168   0.07715167498104595f   // 1/sqrt(168)

typedef unsigned int   uint32;
typedef unsigned short u16;
typedef __attribute__((ext_vector_type(8))) short short8;
typedef __attribute__((ext_vector_type(4))) float f32x4;

#define AS1(p) ((const __attribute__((address_space(1))) void*)(p))
#define AS3(p) ((__attribute__((address_space(3))) void*)(p))

__device__ __forceinline__ u16 f2bf(float f) {            // RNE f32 -> bf16 bits
  uint32 u = __float_as_uint(f);
  return (u16)((u + 0x7FFFu + ((u >> 16) & 1u)) >> 16);
}
__device__ __forceinline__ uint32 pack_bf16(float lo, float hi) {
  uint32 a = __float_as_uint(lo), b = __float_as_uint(hi);
  a = (a + 0x7FFFu + ((a >> 16) & 1u)) >> 16;
  b = (b + 0x7FFFu + ((b >> 16) & 1u)) & 0xFFFF0000u;
  return a | b;
}

__device__ __forceinline__ float wave_reduce(float v) {
#pragma unroll
  for (int o = 32; o > 0; o >>= 1) v += __shfl_down(v, o, 64);
  return v;
}

// c[b,ch] = sum_g x_t[b,g] * from_s2[ch,g],  x_t flat g = j*96+i
__global__ void k_c(const float* __restrict__ x, const float* __restrict__ fs,
                    float* __restrict__ c) {
  const int ch = blockIdx.x, b = blockIdx.y, tid = threadIdx.x;
  const float* xb = x + b * 9216;
  const float* fr = fs + ch * 9216;
  float s = 0.f;
  for (int g = tid; g < 9216; g += 256) {
    s += xb[(g % 96) * 96 + (g / 96)] * fr[g];
  }
  s = wave_reduce(s);
  __shared__ float red[4];
  if ((tid & 63) == 0) red[tid >> 6] = s;
  __syncthreads();
  if (tid == 0) c[b * 121 + ch] = red[0] + red[1] + red[2] + red[3];
}

// psi1[j,i] = (1/sqrt(24)) * sum_n Yk1[n,i] * w1[j,n]
__global__ void k_psi1(const float* __restrict__ Yk1, const float* __restrict__ w1,
                       float* __restrict__ psi1) {
  const int j = blockIdx.x, i = threadIdx.x;
  __shared__ float wsm[24];
  if (i < 24) wsm[i] = w1[j * 24 + i];
  __syncthreads();
  if (i < 121) {
    float s = 0.f;
#pragma unroll
    for (int n = 0; n < 24; ++n) s += Yk1[n * 121 + i] * wsm[n];
    psi1[j * 121 + i] = s * RS24;
  }
}

// hb[b,j, off_l + n*k + m] = bf16( c[b,l*l+m] * psi1[j,l*l+n] ),  K padded 1792
__global__ void k_h(const float* __restrict__ c, const float* __restrict__ psi1,
                    u16* __restrict__ hb) {
  const int j = blockIdx.x, b = blockIdx.y, tid = threadIdx.x;
  __shared__ float cs[121], ps[121];
  if (tid < 121) { cs[tid] = c[b * 121 + tid]; ps[tid] = psi1[j * 121 + tid]; }
  __syncthreads();
  for (int idx = tid; idx < K1P; idx += 256) {
    u16 v = 0;
    if (idx < NC1) {
      int off = 0, l = 0, k = 1;
      while (idx >= off + k * k) { off += k * k; ++l; k += 2; }
      const int r = idx - off, n = r / k, m = r % k;
      v = f2bf(cs[l * l + m] * ps[l * l + n]);
    }
    hb[(size_t)(b * F1_ + j) * K1P + idx] = v;
  }
}

// GEMM1 (MFMA): g[m,n] = bf16( sqrt(2)*relu( sum_k hb[m,k] * D1_to[n,k] ) )
// M=640, N=32000, K=1771 (padded 1792). Tile 128x128, BK=32.
__launch_bounds__(256)
__global__ void k_gemm1_mfma(const u16* __restrict__ A, const float* __restrict__ Bf,
                             u16* __restrict__ C) {
  __shared__ __align__(16) u16 As[128 * 32];
  __shared__ __align__(16) u16 Bs[128 * 32];
  const int tid = threadIdx.x;
  const int lane = tid & 63, w = tid >> 6;
  const int wm = w >> 1, wn = w & 1;
  const int q = lane >> 4, r16 = lane & 15;
  const int m0 = blockIdx.x * 128, n0 = blockIdx.y * 128;

  f32x4 acc[4][4] = {};
  const u16* ag = A + (size_t)(m0 + (tid >> 2)) * K1P + (tid & 3) * 8;

  for (int k0 = 0; k0 < K1P; k0 += 32) {
    // A tile: 2 x 16B async direct-to-LDS per thread
#pragma unroll
    for (int i = 0; i < 2; ++i) {
      __builtin_amdgcn_global_load_lds(AS1(ag + k0 + (size_t)i * 64 * K1P),
                                       AS3((char*)As + i * 4096 + w * 1024),
                                       16, 0, 0);
    }
    // B tile: fp32 loads (row stride 1771, odd) -> RNE bf16 pack -> LDS
#pragma unroll
    for (int i = 0; i < 8; ++i) {
      const int p = i * 256 + tid;
      const int row = p >> 4, c2 = (p & 15) * 2;
      const int kk = k0 + c2;
      const float* bp = Bf + (size_t)(n0 + row) * NC1 + kk;
      const float lo = (kk < NC1) ? bp[0] : 0.f;
      const float hi = (kk + 1 < NC1) ? bp[1] : 0.f;
      ((uint32*)Bs)[row * 16 + (p & 15)] = pack_bf16(lo, hi);
    }
    __syncthreads();
    short8 af[4], bg[4];
#pragma unroll
    for (int mb = 0; mb < 4; ++mb)
      af[mb] = *(const short8*)&As[(wm * 64 + mb * 16 + r16) * 32 + q * 8];
#pragma unroll
    for (int nb = 0; nb < 4; ++nb)
      bg[nb] = *(const short8*)&Bs[(wn * 64 + nb * 16 + r16) * 32 + q * 8];
#pragma unroll
    for (int mb = 0; mb < 4; ++mb)
#pragma unroll
      for (int nb = 0; nb < 4; ++nb)
        acc[mb][nb] = __builtin_amdgcn_mfma_f32_16x16x32_bf16(af[mb], bg[nb], acc[mb][nb], 0, 0, 0);
    __syncthreads();
  }
#pragma unroll
  for (int mb = 0; mb < 4; ++mb) {
#pragma unroll
    for (int nb = 0; nb < 4; ++nb) {
      const int col = n0 + wn * 64 + nb * 16 + r16;
#pragma unroll
      for (int r = 0; r < 4; ++r) {
        const int row = m0 + wm * 64 + mb * 16 + q * 4 + r;
        float v = acc[mb][nb][r];
        v = (v > 0.f) ? v * SQRT2_ : 0.f;
        C[(size_t)row * NG1 + col] = f2bf(v);
      }
    }
  }
}

// GEMM2 (MFMA, split-K=20): h2[m,n] += sum_k g[m,k] * F1_from[n,k]
// M=640, N=286 (tiles padded to 384), K=32000 -> 20 chunks of 1600.
__launch_bounds__(256)
__global__ void k_gemm2_mfma(const u16* __restrict__ A, const float* __restrict__ Bf,
                             float* __restrict__ C) {
  __shared__ __align__(16) u16 As[128 * 32];
  __shared__ __align__(16) u16 Bs[128 * 32];
  const int tid = threadIdx.x;
  const int lane = tid & 63, w = tid >> 6;
  const int wm = w >> 1, wn = w & 1;
  const int q = lane >> 4, r16 = lane & 15;
  const int m0 = blockIdx.x * 128, n0 = blockIdx.y * 128;
  const int ks = blockIdx.z * 1600;

  f32x4 acc[4][4] = {};
  const u16* ag = A + (size_t)(m0 + (tid >> 2)) * NG1 + ks + (tid & 3) * 8;

  for (int kt = 0; kt < 1600; kt += 32) {
#pragma unroll
    for (int i = 0; i < 2; ++i) {
      __builtin_amdgcn_global_load_lds(AS1(ag + kt + (size_t)i * 64 * NG1),
                                       AS3((char*)As + i * 4096 + w * 1024),
                                       16, 0, 0);
    }
    // B tile: float4 loads (row stride 32000, 16B aligned) -> bf16 -> LDS
#pragma unroll
    for (int i = 0; i < 4; ++i) {
      const int idx = i * 256 + tid;
      const int row = idx >> 3, c4 = (idx & 7) * 4;
      const int n = n0 + row;
      float4 v = make_float4(0.f, 0.f, 0.f, 0.f);
      if (n < NC2) v = *(const float4*)(Bf + (size_t)n * NG1 + ks + kt + c4);
      ((uint32*)Bs)[row * 16 + (idx & 7) * 2]     = pack_bf16(v.x, v.y);
      ((uint32*)Bs)[row * 16 + (idx & 7) * 2 + 1] = pack_bf16(v.z, v.w);
    }
    __syncthreads();
    short8 af[4], bg[4];
#pragma unroll
    for (int mb = 0; mb < 4; ++mb)
      af[mb] = *(const short8*)&As[(wm * 64 + mb * 16 + r16) * 32 + q * 8];
#pragma unroll
    for (int nb = 0; nb < 4; ++nb)
      bg[nb] = *(const short8*)&Bs[(wn * 64 + nb * 16 + r16) * 32 + q * 8];
#pragma unroll
    for (int mb = 0; mb < 4; ++mb)
#pragma unroll
      for (int nb = 0; nb < 4; ++nb)
        acc[mb][nb] = __builtin_amdgcn_mfma_f32_16x16x32_bf16(af[mb], bg[nb], acc[mb][nb], 0, 0, 0);
    __syncthreads();
  }
#pragma unroll
  for (int mb = 0; mb < 4; ++mb) {
#pragma unroll
    for (int nb = 0; nb < 4; ++nb) {
      const int col = n0 + wn * 64 + nb * 16 + r16;
      if (col < NC2) {
#pragma unroll
        for (int r = 0; r < 4; ++r) {
          const int row = m0 + wm * 64 + mb * 16 + q * 4 + r;
          atomicAdd(&C[(size_t)row * NC2 + col], acc[mb][nb][r]);
        }
      }
    }
  }
}

// psi2[i,j,c] = (1/sqrt(168)) * sum_n Dk2[n,c] * w2[i,j,n]
__global__ void k_psi2(const float* __restrict__ Dk2, const float* __restrict__ w2,
                       float* __restrict__ psi2) {
  const int blk = blockIdx.x, tid = threadIdx.x;   // blk = i*40+j
  __shared__ float w2s[168];
  if (tid < 168) w2s[tid] = w2[blk * 168 + tid];
  __syncthreads();
  for (int cc = tid; cc < NC2; cc += 256) {
    float s = 0.f;
    for (int n = 0; n < 168; ++n) s += Dk2[n * NC2 + cc] * w2s[n];
    psi2[blk * NC2 + cc] = s * RS168;
  }
}

// per-l SO(3)xSO(3) conv
__global__ void k_step7(const float* __restrict__ h2, const float* __restrict__ psi2,
                        float* __restrict__ h3) {
  const int j = blockIdx.x, b = blockIdx.y, tid = threadIdx.x;
  __shared__ float sh[20 * 286];
  __shared__ float sp[20 * 286];
  for (int e = tid; e < 20 * 286; e += 256) {
    const int i = e / 286, cc = e % 286;
    sh[e] = h2[(b * F1_ + i) * NC2 + cc];
    sp[e] = psi2[(i * F2_ + j) * NC2 + cc];
  }
  __syncthreads();
  for (int cidx = tid; cidx < NC2; cidx += 256) {
    int off = 0, l = 0, k = 1;
    while (cidx >= off + k * k) { off += k * k; ++l; k += 2; }
    const int r = cidx - off, v = r / k, m = r % k;
    float acc = 0.f;
    for (int i = 0; i < 20; ++i) {
      const float* hbp = &sh[i * 286 + off];
      const float* pb = &sp[i * 286 + off];
      for (int u = 0; u < k; ++u) acc += hbp[u * k + m] * pb[u * k + v];
    }
    h3[(b * F2_ + j) * NC2 + cidx] = acc * rsqrtf(20.f * (float)k);
  }
}

// GEMM3 fused with final activation+reduction (fp32):
// out[m] += sqrt(2) * sum_n relu( sum_k h3[m,k]*D2_to[n,k] ) * F2_from[n]
__launch_bounds__(256)
__global__ void k_gemm3(const float* __restrict__ A, const float* __restrict__ Bm,
                        const float* __restrict__ wv, float* __restrict__ out) {
  __shared__ float As[16][68];
  __shared__ float Bs[16][68];
  __shared__ float red[64][17];
  const int m0 = blockIdx.x * 64;
  const int n0 = blockIdx.y * 64;
  const int tid = threadIdx.x, tx = tid & 15, ty = tid >> 4;
  float acc[4][4] = {};
  const int K = NC2;
  for (int k0 = 0; k0 < K; k0 += 16) {
#pragma unroll
    for (int i = 0; i < 4; ++i) {
      const int e = tid + 256 * i, row = e >> 4, col = e & 15, kk = k0 + col;
      As[col][row] = (kk < K) ? A[(m0 + row) * K + kk] : 0.f;
      Bs[col][row] = (kk < K) ? Bm[(n0 + row) * K + kk] : 0.f;
    }
    __syncthreads();
#pragma unroll
    for (int kk = 0; kk < 16; ++kk) {
      const float4 av = *(const float4*)&As[kk][ty * 4];
      const float4 bv = *(const float4*)&Bs[kk][tx * 4];
      const float a0[4] = {av.x, av.y, av.z, av.w};
      const float b0[4] = {bv.x, bv.y, bv.z, bv.w};
#pragma unroll
      for (int i = 0; i < 4; ++i)
#pragma unroll
        for (int j = 0; j < 4; ++j) acc[i][j] += a0[i] * b0[j];
    }
    __syncthreads();
  }
#pragma unroll
  for (int i = 0; i < 4; ++i) {
    float t = 0.f;
#pragma unroll
    for (int j = 0; j < 4; ++j) {
      float v = acc[i][j];
      v = (v > 0.f) ? v : 0.f;
      t += v * wv[n0 + tx * 4 + j];
    }
    red[ty * 4 + i][tx] = t;
  }
  __syncthreads();
  if (tid < 64) {
    float t = 0.f;
#pragma unroll
    for (int qq = 0; qq < 16; ++qq) t += red[tid][qq];
    atomicAdd(&out[m0 + tid], t * SQRT2_);
  }
}

extern "C" void kernel_launch(void* const* d_in, const int* in_sizes, int n_in,
                              void* d_out, int out_size, void* d_ws, size_t ws_size,
                              hipStream_t stream) {
  const float* x       = (const float*)d_in[0];
  const float* w1      = (const float*)d_in[1];
  const float* w2      = (const float*)d_in[2];
  const float* Yk1     = (const float*)d_in[3];
  const float* Dk2     = (const float*)d_in[4];
  const float* from_s2 = (const float*)d_in[5];
  const float* D1_to   = (const float*)d_in[6];
  const float* F1_from = (const float*)d_in[7];
  const float* D2_to   = (const float*)d_in[8];
  const float* F2_from = (const float*)d_in[9];
  float* out = (float*)d_out;

  float* ws = (float*)d_ws;
  float* c    = ws + 0;            //   3,872
  float* psi1 = ws + 3872;         //   2,420
  float* h2   = ws + 6292;         // 183,040
  float* psi2 = ws + 189332;       // 228,800
  float* h3   = ws + 418132;       // 366,080
  u16*   hb   = (u16*)(ws + 784212);    // 640*1792  bf16 = 2.29 MB
  u16*   g    = (u16*)(ws + 1357652);   // 640*32000 bf16 = 40.96 MB
  // total ~46.4 MB

  k_c   <<<dim3(121, 32), 256, 0, stream>>>(x, from_s2, c);
  k_psi1<<<dim3(20),      128, 0, stream>>>(Yk1, w1, psi1);
  k_h   <<<dim3(20, 32),  256, 0, stream>>>(c, psi1, hb);

  k_gemm1_mfma<<<dim3(5, 250), 256, 0, stream>>>(hb, D1_to, g);

  hipMemsetAsync(h2, 0, (size_t)640 * 286 * sizeof(float), stream);
  k_gemm2_mfma<<<dim3(5, 3, 20), 256, 0, stream>>>(g, F1_from, h2);

  k_psi2 <<<dim3(800),    256, 0, stream>>>(Dk2, w2, psi2);
  k_step7<<<dim3(40, 32), 256, 0, stream>>>(h2, psi2, h3);

  hipMemsetAsync(out, 0, (size_t)1280 * sizeof(float), stream);
  k_gemm3<<<dim3(20, 108), 256, 0, stream>>>(h3, D2_to, F2_from, out);
}

// Round 3
// 776.146 us; speedup vs baseline: 2.7870x; 1.5962x over previous
//
#include <hip/hip_runtime.h>
#include <hip/hip_bf16.h>
#include <math.h>

// ---------------------------------------------------------------------------
// S2ConvNetModified pipeline.
// Round 3: pre-convert D1_to/F1_from/D2_to to bf16 (when ws allows), all three
// GEMMs in m97-style MFMA with both operands via global_load_lds width=16.
// XCD-aware swizzle on GEMM1. Fallback to round-2 on-the-fly-convert GEMMs
// if ws_size < 183 MB.
// ---------------------------------------------------------------------------

#define B_      32
#define F1_     20
#define F2_     40
#define NC1     1771
#define K1P     1792          // NC1 padded to multiple of 32
#define NG1     32000
#define NC2     286
#define K2P     288           // NC2 padded to multiple of 32
#define NG2     6912
#define SQRT2_  1.41421356237309515f
#define RS24    0.20412414523193154f   // 1/sqrt(24)
#define RS168   0.07715167498104595f   // 1/sqrt(168)

typedef unsigned int   uint32;
typedef unsigned short u16;
typedef __attribute__((ext_vector_type(8))) short short8;
typedef __attribute__((ext_vector_type(4))) float f32x4;

#define AS1(p) ((const __attribute__((address_space(1))) void*)(p))
#define AS3(p) ((__attribute__((address_space(3))) void*)(p))

__device__ __forceinline__ u16 f2bf(float f) {            // RNE f32 -> bf16 bits
  uint32 u = __float_as_uint(f);
  return (u16)((u + 0x7FFFu + ((u >> 16) & 1u)) >> 16);
}
__device__ __forceinline__ uint32 pack_bf16(float lo, float hi) {
  uint32 a = __float_as_uint(lo), b = __float_as_uint(hi);
  a = (a + 0x7FFFu + ((a >> 16) & 1u)) >> 16;
  b = (b + 0x7FFFu + ((b >> 16) & 1u)) & 0xFFFF0000u;
  return a | b;
}

__device__ __forceinline__ float wave_reduce(float v) {
#pragma unroll
  for (int o = 32; o > 0; o >>= 1) v += __shfl_down(v, o, 64);
  return v;
}

// ------------------------- small prologue kernels --------------------------

__global__ void k_c(const float* __restrict__ x, const float* __restrict__ fs,
                    float* __restrict__ c) {
  const int ch = blockIdx.x, b = blockIdx.y, tid = threadIdx.x;
  const float* xb = x + b * 9216;
  const float* fr = fs + ch * 9216;
  float s = 0.f;
  for (int g = tid; g < 9216; g += 256) {
    s += xb[(g % 96) * 96 + (g / 96)] * fr[g];
  }
  s = wave_reduce(s);
  __shared__ float red[4];
  if ((tid & 63) == 0) red[tid >> 6] = s;
  __syncthreads();
  if (tid == 0) c[b * 121 + ch] = red[0] + red[1] + red[2] + red[3];
}

__global__ void k_psi1(const float* __restrict__ Yk1, const float* __restrict__ w1,
                       float* __restrict__ psi1) {
  const int j = blockIdx.x, i = threadIdx.x;
  __shared__ float wsm[24];
  if (i < 24) wsm[i] = w1[j * 24 + i];
  __syncthreads();
  if (i < 121) {
    float s = 0.f;
#pragma unroll
    for (int n = 0; n < 24; ++n) s += Yk1[n * 121 + i] * wsm[n];
    psi1[j * 121 + i] = s * RS24;
  }
}

__global__ void k_h(const float* __restrict__ c, const float* __restrict__ psi1,
                    u16* __restrict__ hb) {
  const int j = blockIdx.x, b = blockIdx.y, tid = threadIdx.x;
  __shared__ float cs[121], ps[121];
  if (tid < 121) { cs[tid] = c[b * 121 + tid]; ps[tid] = psi1[j * 121 + tid]; }
  __syncthreads();
  for (int idx = tid; idx < K1P; idx += 256) {
    u16 v = 0;
    if (idx < NC1) {
      int off = 0, l = 0, k = 1;
      while (idx >= off + k * k) { off += k * k; ++l; k += 2; }
      const int r = idx - off, n = r / k, m = r % k;
      v = f2bf(cs[l * l + m] * ps[l * l + n]);
    }
    hb[(size_t)(b * F1_ + j) * K1P + idx] = v;
  }
}

// ------------------------- bf16 convert kernels ----------------------------

// D1_to [32000,1771] fp32 -> [32000,1792] bf16 (zero pad)
__global__ void k_cvt1(const float* __restrict__ in, uint32* __restrict__ out) {
  const int total = 32000 * 896;
  for (int id = blockIdx.x * 256 + threadIdx.x; id < total; id += gridDim.x * 256) {
    const int r = id / 896, c2 = id % 896, cc = c2 * 2;
    const float* p = in + (size_t)r * NC1 + cc;
    const float lo = (cc < NC1) ? p[0] : 0.f;
    const float hi = (cc + 1 < NC1) ? p[1] : 0.f;
    out[id] = pack_bf16(lo, hi);
  }
}

// F1_from [286,32000] fp32 -> bf16 (no pad needed)
__global__ void k_cvt2(const float* __restrict__ in, uint32* __restrict__ out) {
  const int total = 286 * 16000;
  for (int id = blockIdx.x * 256 + threadIdx.x; id < total; id += gridDim.x * 256) {
    out[id] = pack_bf16(in[2 * id], in[2 * id + 1]);
  }
}

// D2_to [6912,286] fp32 -> [6912,288] bf16 (zero pad)
__global__ void k_cvt3(const float* __restrict__ in, uint32* __restrict__ out) {
  const int total = 6912 * 144;
  for (int id = blockIdx.x * 256 + threadIdx.x; id < total; id += gridDim.x * 256) {
    const int r = id / 144, c2 = id % 144, cc = c2 * 2;
    const float* p = in + (size_t)r * NC2 + cc;
    const float lo = (cc < NC2) ? p[0] : 0.f;
    const float hi = (cc + 1 < NC2) ? p[1] : 0.f;
    out[id] = pack_bf16(lo, hi);
  }
}

// ------------------------- MFMA GEMMs (bf16 x bf16) ------------------------

// GEMM1: g[m,n] = bf16( sqrt(2)*relu( sum_k hb[m,k] * D1bf[n,k] ) )
// M=640, N=32000, K=1792. Tile 128x128, BK=32. XCD swizzle: groups of 40
// blocks = 8 n-tiles x 5 m-tiles; same-n blocks are 8 apart -> same XCD.
__launch_bounds__(256)
__global__ void k_gemm1_v3(const u16* __restrict__ A, const u16* __restrict__ B,
                           u16* __restrict__ C) {
  __shared__ __align__(16) u16 As[128 * 32];
  __shared__ __align__(16) u16 Bs[128 * 32];
  const int bid = blockIdx.x;                // 0..1249
  const int g = bid / 40, loc = bid % 40;
  int nt, mt;
  if (g < 31) { nt = g * 8 + (loc & 7); mt = loc >> 3; }
  else        { nt = 248 + (loc & 1);  mt = loc >> 1; }
  const int m0 = mt * 128, n0 = nt * 128;
  const int tid = threadIdx.x;
  const int lane = tid & 63, w = tid >> 6;
  const int wm = w >> 1, wn = w & 1;
  const int q = lane >> 4, r16 = lane & 15;

  f32x4 acc[4][4] = {};
  const u16* ag = A + (size_t)(m0 + (tid >> 2)) * K1P + (tid & 3) * 8;
  const u16* bg = B + (size_t)(n0 + (tid >> 2)) * K1P + (tid & 3) * 8;

  for (int k0 = 0; k0 < K1P; k0 += 32) {
#pragma unroll
    for (int i = 0; i < 2; ++i) {
      __builtin_amdgcn_global_load_lds(AS1(ag + k0 + (size_t)i * 64 * K1P),
                                       AS3((char*)As + i * 4096 + w * 1024), 16, 0, 0);
      __builtin_amdgcn_global_load_lds(AS1(bg + k0 + (size_t)i * 64 * K1P),
                                       AS3((char*)Bs + i * 4096 + w * 1024), 16, 0, 0);
    }
    __syncthreads();
    short8 af[4], bf[4];
#pragma unroll
    for (int mb = 0; mb < 4; ++mb)
      af[mb] = *(const short8*)&As[(wm * 64 + mb * 16 + r16) * 32 + q * 8];
#pragma unroll
    for (int nb = 0; nb < 4; ++nb)
      bf[nb] = *(const short8*)&Bs[(wn * 64 + nb * 16 + r16) * 32 + q * 8];
#pragma unroll
    for (int mb = 0; mb < 4; ++mb)
#pragma unroll
      for (int nb = 0; nb < 4; ++nb)
        acc[mb][nb] = __builtin_amdgcn_mfma_f32_16x16x32_bf16(af[mb], bf[nb], acc[mb][nb], 0, 0, 0);
    __syncthreads();
  }
#pragma unroll
  for (int mb = 0; mb < 4; ++mb) {
#pragma unroll
    for (int nb = 0; nb < 4; ++nb) {
      const int col = n0 + wn * 64 + nb * 16 + r16;
#pragma unroll
      for (int r = 0; r < 4; ++r) {
        const int row = m0 + wm * 64 + mb * 16 + q * 4 + r;
        float v = acc[mb][nb][r];
        v = (v > 0.f) ? v * SQRT2_ : 0.f;
        C[(size_t)row * NG1 + col] = f2bf(v);
      }
    }
  }
}

// GEMM2 (split-K=20): h2[m,n] += sum_k g[m,k] * F1bf[n,k]
// M=640, N=286 (3 n-tiles, rows clamped), K=32000 -> 20 chunks of 1600.
__launch_bounds__(256)
__global__ void k_gemm2_v3(const u16* __restrict__ A, const u16* __restrict__ B,
                           float* __restrict__ C) {
  __shared__ __align__(16) u16 As[128 * 32];
  __shared__ __align__(16) u16 Bs[128 * 32];
  const int m0 = blockIdx.x * 128, n0 = blockIdx.y * 128;
  const int ks = blockIdx.z * 1600;
  const int tid = threadIdx.x;
  const int lane = tid & 63, w = tid >> 6;
  const int wm = w >> 1, wn = w & 1;
  const int q = lane >> 4, r16 = lane & 15;

  f32x4 acc[4][4] = {};
  const u16* ag = A + (size_t)(m0 + (tid >> 2)) * NG1 + ks + (tid & 3) * 8;
  int rb0 = n0 + (tid >> 2);        if (rb0 > 285) rb0 = 285;
  int rb1 = n0 + (tid >> 2) + 64;   if (rb1 > 285) rb1 = 285;
  const u16* bg0 = B + (size_t)rb0 * NG1 + ks + (tid & 3) * 8;
  const u16* bg1 = B + (size_t)rb1 * NG1 + ks + (tid & 3) * 8;

  for (int kt = 0; kt < 1600; kt += 32) {
#pragma unroll
    for (int i = 0; i < 2; ++i) {
      __builtin_amdgcn_global_load_lds(AS1(ag + kt + (size_t)i * 64 * NG1),
                                       AS3((char*)As + i * 4096 + w * 1024), 16, 0, 0);
    }
    __builtin_amdgcn_global_load_lds(AS1(bg0 + kt), AS3((char*)Bs + w * 1024), 16, 0, 0);
    __builtin_amdgcn_global_load_lds(AS1(bg1 + kt), AS3((char*)Bs + 4096 + w * 1024), 16, 0, 0);
    __syncthreads();
    short8 af[4], bf[4];
#pragma unroll
    for (int mb = 0; mb < 4; ++mb)
      af[mb] = *(const short8*)&As[(wm * 64 + mb * 16 + r16) * 32 + q * 8];
#pragma unroll
    for (int nb = 0; nb < 4; ++nb)
      bf[nb] = *(const short8*)&Bs[(wn * 64 + nb * 16 + r16) * 32 + q * 8];
#pragma unroll
    for (int mb = 0; mb < 4; ++mb)
#pragma unroll
      for (int nb = 0; nb < 4; ++nb)
        acc[mb][nb] = __builtin_amdgcn_mfma_f32_16x16x32_bf16(af[mb], bf[nb], acc[mb][nb], 0, 0, 0);
    __syncthreads();
  }
#pragma unroll
  for (int mb = 0; mb < 4; ++mb) {
#pragma unroll
    for (int nb = 0; nb < 4; ++nb) {
      const int col = n0 + wn * 64 + nb * 16 + r16;
      if (col < NC2) {
#pragma unroll
        for (int r = 0; r < 4; ++r) {
          const int row = m0 + wm * 64 + mb * 16 + q * 4 + r;
          atomicAdd(&C[(size_t)row * NC2 + col], acc[mb][nb][r]);
        }
      }
    }
  }
}

// GEMM3 fused epilogue: out[m] += sqrt(2)*sum_n relu(sum_k h3b[m,k]*D2bf[n,k])*F2_from[n]
// M=1280, N=6912, K=288.
__launch_bounds__(256)
__global__ void k_gemm3_v3(const u16* __restrict__ A, const u16* __restrict__ B,
                           const float* __restrict__ wv, float* __restrict__ out) {
  __shared__ __align__(16) u16 As[128 * 32];
  __shared__ __align__(16) u16 Bs[128 * 32];
  __shared__ float red[128][33];
  const int m0 = blockIdx.x * 128, n0 = blockIdx.y * 128;
  const int tid = threadIdx.x;
  const int lane = tid & 63, w = tid >> 6;
  const int wm = w >> 1, wn = w & 1;
  const int q = lane >> 4, r16 = lane & 15;

  f32x4 acc[4][4] = {};
  const u16* ag = A + (size_t)(m0 + (tid >> 2)) * K2P + (tid & 3) * 8;
  const u16* bg = B + (size_t)(n0 + (tid >> 2)) * K2P + (tid & 3) * 8;

  for (int k0 = 0; k0 < K2P; k0 += 32) {
#pragma unroll
    for (int i = 0; i < 2; ++i) {
      __builtin_amdgcn_global_load_lds(AS1(ag + k0 + (size_t)i * 64 * K2P),
                                       AS3((char*)As + i * 4096 + w * 1024), 16, 0, 0);
      __builtin_amdgcn_global_load_lds(AS1(bg + k0 + (size_t)i * 64 * K2P),
                                       AS3((char*)Bs + i * 4096 + w * 1024), 16, 0, 0);
    }
    __syncthreads();
    short8 af[4], bf[4];
#pragma unroll
    for (int mb = 0; mb < 4; ++mb)
      af[mb] = *(const short8*)&As[(wm * 64 + mb * 16 + r16) * 32 + q * 8];
#pragma unroll
    for (int nb = 0; nb < 4; ++nb)
      bf[nb] = *(const short8*)&Bs[(wn * 64 + nb * 16 + r16) * 32 + q * 8];
#pragma unroll
    for (int mb = 0; mb < 4; ++mb)
#pragma unroll
      for (int nb = 0; nb < 4; ++nb)
        acc[mb][nb] = __builtin_amdgcn_mfma_f32_16x16x32_bf16(af[mb], bf[nb], acc[mb][nb], 0, 0, 0);
    __syncthreads();
  }
  // fused relu * F2_from[n], reduce over n
  float wvv[4];
#pragma unroll
  for (int nb = 0; nb < 4; ++nb) wvv[nb] = wv[n0 + wn * 64 + nb * 16 + r16];
#pragma unroll
  for (int mb = 0; mb < 4; ++mb) {
#pragma unroll
    for (int r = 0; r < 4; ++r) {
      const int rowl = wm * 64 + mb * 16 + q * 4 + r;
      float t = 0.f;
#pragma unroll
      for (int nb = 0; nb < 4; ++nb) {
        float v = acc[mb][nb][r];
        v = (v > 0.f) ? v : 0.f;
        t += v * wvv[nb];
      }
      red[rowl][wn * 16 + r16] = t;
    }
  }
  __syncthreads();
  if (tid < 128) {
    float s = 0.f;
#pragma unroll
    for (int cc = 0; cc < 32; ++cc) s += red[tid][cc];
    atomicAdd(&out[m0 + tid], s * SQRT2_);
  }
}

// ------------------- fallback GEMM1/GEMM2 (round-2, on-the-fly cvt) --------

__launch_bounds__(256)
__global__ void k_gemm1_mfma(const u16* __restrict__ A, const float* __restrict__ Bf,
                             u16* __restrict__ C) {
  __shared__ __align__(16) u16 As[128 * 32];
  __shared__ __align__(16) u16 Bs[128 * 32];
  const int tid = threadIdx.x;
  const int lane = tid & 63, w = tid >> 6;
  const int wm = w >> 1, wn = w & 1;
  const int q = lane >> 4, r16 = lane & 15;
  const int m0 = blockIdx.x * 128, n0 = blockIdx.y * 128;

  f32x4 acc[4][4] = {};
  const u16* ag = A + (size_t)(m0 + (tid >> 2)) * K1P + (tid & 3) * 8;

  for (int k0 = 0; k0 < K1P; k0 += 32) {
#pragma unroll
    for (int i = 0; i < 2; ++i) {
      __builtin_amdgcn_global_load_lds(AS1(ag + k0 + (size_t)i * 64 * K1P),
                                       AS3((char*)As + i * 4096 + w * 1024), 16, 0, 0);
    }
#pragma unroll
    for (int i = 0; i < 8; ++i) {
      const int p = i * 256 + tid;
      const int row = p >> 4, c2 = (p & 15) * 2;
      const int kk = k0 + c2;
      const float* bp = Bf + (size_t)(n0 + row) * NC1 + kk;
      const float lo = (kk < NC1) ? bp[0] : 0.f;
      const float hi = (kk + 1 < NC1) ? bp[1] : 0.f;
      ((uint32*)Bs)[row * 16 + (p & 15)] = pack_bf16(lo, hi);
    }
    __syncthreads();
    short8 af[4], bf[4];
#pragma unroll
    for (int mb = 0; mb < 4; ++mb)
      af[mb] = *(const short8*)&As[(wm * 64 + mb * 16 + r16) * 32 + q * 8];
#pragma unroll
    for (int nb = 0; nb < 4; ++nb)
      bf[nb] = *(const short8*)&Bs[(wn * 64 + nb * 16 + r16) * 32 + q * 8];
#pragma unroll
    for (int mb = 0; mb < 4; ++mb)
#pragma unroll
      for (int nb = 0; nb < 4; ++nb)
        acc[mb][nb] = __builtin_amdgcn_mfma_f32_16x16x32_bf16(af[mb], bf[nb], acc[mb][nb], 0, 0, 0);
    __syncthreads();
  }
#pragma unroll
  for (int mb = 0; mb < 4; ++mb) {
#pragma unroll
    for (int nb = 0; nb < 4; ++nb) {
      const int col = n0 + wn * 64 + nb * 16 + r16;
#pragma unroll
      for (int r = 0; r < 4; ++r) {
        const int row = m0 + wm * 64 + mb * 16 + q * 4 + r;
        float v = acc[mb][nb][r];
        v = (v > 0.f) ? v * SQRT2_ : 0.f;
        C[(size_t)row * NG1 + col] = f2bf(v);
      }
    }
  }
}

__launch_bounds__(256)
__global__ void k_gemm2_mfma(const u16* __restrict__ A, const float* __restrict__ Bf,
                             float* __restrict__ C) {
  __shared__ __align__(16) u16 As[128 * 32];
  __shared__ __align__(16) u16 Bs[128 * 32];
  const int tid = threadIdx.x;
  const int lane = tid & 63, w = tid >> 6;
  const int wm = w >> 1, wn = w & 1;
  const int q = lane >> 4, r16 = lane & 15;
  const int m0 = blockIdx.x * 128, n0 = blockIdx.y * 128;
  const int ks = blockIdx.z * 1600;

  f32x4 acc[4][4] = {};
  const u16* ag = A + (size_t)(m0 + (tid >> 2)) * NG1 + ks + (tid & 3) * 8;

  for (int kt = 0; kt < 1600; kt += 32) {
#pragma unroll
    for (int i = 0; i < 2; ++i) {
      __builtin_amdgcn_global_load_lds(AS1(ag + kt + (size_t)i * 64 * NG1),
                                       AS3((char*)As + i * 4096 + w * 1024), 16, 0, 0);
    }
#pragma unroll
    for (int i = 0; i < 4; ++i) {
      const int idx = i * 256 + tid;
      const int row = idx >> 3, c4 = (idx & 7) * 4;
      const int n = n0 + row;
      float4 v = make_float4(0.f, 0.f, 0.f, 0.f);
      if (n < NC2) v = *(const float4*)(Bf + (size_t)n * NG1 + ks + kt + c4);
      ((uint32*)Bs)[row * 16 + (idx & 7) * 2]     = pack_bf16(v.x, v.y);
      ((uint32*)Bs)[row * 16 + (idx & 7) * 2 + 1] = pack_bf16(v.z, v.w);
    }
    __syncthreads();
    short8 af[4], bf[4];
#pragma unroll
    for (int mb = 0; mb < 4; ++mb)
      af[mb] = *(const short8*)&As[(wm * 64 + mb * 16 + r16) * 32 + q * 8];
#pragma unroll
    for (int nb = 0; nb < 4; ++nb)
      bf[nb] = *(const short8*)&Bs[(wn * 64 + nb * 16 + r16) * 32 + q * 8];
#pragma unroll
    for (int mb = 0; mb < 4; ++mb)
#pragma unroll
      for (int nb = 0; nb < 4; ++nb)
        acc[mb][nb] = __builtin_amdgcn_mfma_f32_16x16x32_bf16(af[mb], bf[nb], acc[mb][nb], 0, 0, 0);
    __syncthreads();
  }
#pragma unroll
  for (int mb = 0; mb < 4; ++mb) {
#pragma unroll
    for (int nb = 0; nb < 4; ++nb) {
      const int col = n0 + wn * 64 + nb * 16 + r16;
      if (col < NC2) {
#pragma unroll
        for (int r = 0; r < 4; ++r) {
          const int row = m0 + wm * 64 + mb * 16 + q * 4 + r;
          atomicAdd(&C[(size_t)row * NC2 + col], acc[mb][nb][r]);
        }
      }
    }
  }
}

// ------------------------- mid/tail kernels --------------------------------

__global__ void k_psi2(const float* __restrict__ Dk2, const float* __restrict__ w2,
                       float* __restrict__ psi2) {
  const int blk = blockIdx.x, tid = threadIdx.x;   // blk = i*40+j
  __shared__ float w2s[168];
  if (tid < 168) w2s[tid] = w2[blk * 168 + tid];
  __syncthreads();
  for (int cc = tid; cc < NC2; cc += 256) {
    float s = 0.f;
    for (int n = 0; n < 168; ++n) s += Dk2[n * NC2 + cc] * w2s[n];
    psi2[blk * NC2 + cc] = s * RS168;
  }
}

// per-l SO(3)xSO(3) conv; writes bf16 padded to K2P=288
__global__ void k_step7(const float* __restrict__ h2, const float* __restrict__ psi2,
                        u16* __restrict__ h3b) {
  const int j = blockIdx.x, b = blockIdx.y, tid = threadIdx.x;
  __shared__ float sh[20 * 286];
  __shared__ float sp[20 * 286];
  for (int e = tid; e < 20 * 286; e += 256) {
    const int i = e / 286, cc = e % 286;
    sh[e] = h2[(b * F1_ + i) * NC2 + cc];
    sp[e] = psi2[(i * F2_ + j) * NC2 + cc];
  }
  __syncthreads();
  for (int cidx = tid; cidx < K2P; cidx += 256) {
    u16 ov = 0;
    if (cidx < NC2) {
      int off = 0, l = 0, k = 1;
      while (cidx >= off + k * k) { off += k * k; ++l; k += 2; }
      const int r = cidx - off, v = r / k, m = r % k;
      float acc = 0.f;
      for (int i = 0; i < 20; ++i) {
        const float* hbp = &sh[i * 286 + off];
        const float* pb = &sp[i * 286 + off];
        for (int u = 0; u < k; ++u) acc += hbp[u * k + m] * pb[u * k + v];
      }
      ov = f2bf(acc * rsqrtf(20.f * (float)k));
    }
    h3b[(size_t)(b * F2_ + j) * K2P + cidx] = ov;
  }
}

// ------------------------------- launcher ----------------------------------

extern "C" void kernel_launch(void* const* d_in, const int* in_sizes, int n_in,
                              void* d_out, int out_size, void* d_ws, size_t ws_size,
                              hipStream_t stream) {
  const float* x       = (const float*)d_in[0];
  const float* w1      = (const float*)d_in[1];
  const float* w2      = (const float*)d_in[2];
  const float* Yk1     = (const float*)d_in[3];
  const float* Dk2     = (const float*)d_in[4];
  const float* from_s2 = (const float*)d_in[5];
  const float* D1_to   = (const float*)d_in[6];
  const float* F1_from = (const float*)d_in[7];
  const float* D2_to   = (const float*)d_in[8];
  const float* F2_from = (const float*)d_in[9];
  float* out = (float*)d_out;

  float* ws = (float*)d_ws;
  // base layout (floats)
  float* c    = ws + 0;            //   3,872
  float* psi1 = ws + 3872;         //   2,420
  float* h2   = ws + 6292;         // 183,040
  float* psi2 = ws + 189332;       // 228,800
  u16*   h3b  = (u16*)(ws + 418132);      // 1280*288 u16  = 184,320 f
  u16*   hb   = (u16*)(ws + 602452);      // 640*1792 u16  = 573,440 f
  u16*   g    = (u16*)(ws + 1175892);     // 640*32000 u16 = 10,240,000 f
  u16*   D2bf = (u16*)(ws + 11415892);    // 6912*288 u16  = 995,328 f
  // big-path extras
  u16*   F1bf = (u16*)(ws + 12411220);    // 286*32000 u16 = 4,576,000 f
  u16*   D1bf = (u16*)(ws + 16987220);    // 32000*1792 u16= 28,672,000 f
  const size_t BIG_NEED = (size_t)45659220 * 4;   // ~182.6 MB
  const bool big = ws_size >= BIG_NEED;

  k_c   <<<dim3(121, 32), 256, 0, stream>>>(x, from_s2, c);
  k_psi1<<<dim3(20),      128, 0, stream>>>(Yk1, w1, psi1);
  k_h   <<<dim3(20, 32),  256, 0, stream>>>(c, psi1, hb);
  k_cvt3<<<dim3(1024),    256, 0, stream>>>(D2_to, (uint32*)D2bf);

  if (big) {
    k_cvt1<<<dim3(8192), 256, 0, stream>>>(D1_to, (uint32*)D1bf);
    k_cvt2<<<dim3(4096), 256, 0, stream>>>(F1_from, (uint32*)F1bf);
    k_gemm1_v3<<<dim3(1250), 256, 0, stream>>>(hb, D1bf, g);
    hipMemsetAsync(h2, 0, (size_t)640 * 286 * sizeof(float), stream);
    k_gemm2_v3<<<dim3(5, 3, 20), 256, 0, stream>>>(g, F1bf, h2);
  } else {
    k_gemm1_mfma<<<dim3(5, 250), 256, 0, stream>>>(hb, D1_to, g);
    hipMemsetAsync(h2, 0, (size_t)640 * 286 * sizeof(float), stream);
    k_gemm2_mfma<<<dim3(5, 3, 20), 256, 0, stream>>>(g, F1_from, h2);
  }

  k_psi2 <<<dim3(800),    256, 0, stream>>>(Dk2, w2, psi2);
  k_step7<<<dim3(40, 32), 256, 0, stream>>>(h2, psi2, h3b);

  hipMemsetAsync(out, 0, (size_t)1280 * sizeof(float), stream);
  k_gemm3_v3<<<dim3(10, 54), 256, 0, stream>>>(h3b, D2bf, F2_from, out);
}

// Round 4
// 674.806 us; speedup vs baseline: 3.2055x; 1.1502x over previous
//
#include <hip/hip_runtime.h>
#include <hip/hip_bf16.h>
#include <math.h>

// ---------------------------------------------------------------------------
// S2ConvNetModified pipeline.
// Round 4: triple-buffered MFMA K-loops (one barrier/iter, vmcnt(4) — loads
// stay in flight across the barrier, AITER-style). Coalesced k_c via x
// transpose. bf16 pre-converted weights (proven path).
// ---------------------------------------------------------------------------

#define B_      32
#define F1_     20
#define F2_     40
#define NC1     1771
#define K1P     1792          // NC1 padded to multiple of 32
#define NG1     32000
#define NC2     286
#define K2P     288           // NC2 padded to multiple of 32
#define NG2     6912
#define SQRT2_  1.41421356237309515f
#define RS24    0.20412414523193154f   // 1/sqrt(24)
#define RS168   0.07715167498104595f   // 1/sqrt(168)

typedef unsigned int   uint32;
typedef unsigned short u16;
typedef __attribute__((ext_vector_type(8))) short short8;
typedef __attribute__((ext_vector_type(4))) float f32x4;

#define AS1(p) ((const __attribute__((address_space(1))) void*)(p))
#define AS3(p) ((__attribute__((address_space(3))) void*)(p))

// s_waitcnt imm: vmcnt[3:0]=4, expcnt=7 (no wait), lgkmcnt=0xF (no wait), vmcnt[5:4]=0
#define WAITCNT_VM4 0x0F74

__device__ __forceinline__ u16 f2bf(float f) {            // RNE f32 -> bf16 bits
  uint32 u = __float_as_uint(f);
  return (u16)((u + 0x7FFFu + ((u >> 16) & 1u)) >> 16);
}
__device__ __forceinline__ uint32 pack_bf16(float lo, float hi) {
  uint32 a = __float_as_uint(lo), b = __float_as_uint(hi);
  a = (a + 0x7FFFu + ((a >> 16) & 1u)) >> 16;
  b = (b + 0x7FFFu + ((b >> 16) & 1u)) & 0xFFFF0000u;
  return a | b;
}

__device__ __forceinline__ float wave_reduce(float v) {
#pragma unroll
  for (int o = 32; o > 0; o >>= 1) v += __shfl_down(v, o, 64);
  return v;
}

// ------------------------- small prologue kernels --------------------------

// x [32,96,96] -> x_t [32, 9216] with x_t[b, j*96+i] = x[b, i*96+j]
__global__ void k_xt(const float* __restrict__ x, float* __restrict__ xt) {
  __shared__ float t[32][33];
  const int b = blockIdx.z, i0 = blockIdx.x * 32, j0 = blockIdx.y * 32;
  const int tx = threadIdx.x & 31, ty0 = threadIdx.x >> 5;
  const float* xb = x + b * 9216;
  float* xtb = xt + b * 9216;
#pragma unroll
  for (int r = 0; r < 4; ++r) {
    const int ty = ty0 + r * 8;
    t[ty][tx] = xb[(i0 + ty) * 96 + j0 + tx];
  }
  __syncthreads();
#pragma unroll
  for (int r = 0; r < 4; ++r) {
    const int ty = ty0 + r * 8;
    xtb[(j0 + ty) * 96 + i0 + tx] = t[tx][ty];
  }
}

// c[b,ch] = sum_g x_t[b,g] * from_s2[ch,g]  (fully coalesced, float4)
__global__ void k_c2(const float* __restrict__ xt, const float* __restrict__ fs,
                     float* __restrict__ c) {
  const int ch = blockIdx.x, b = blockIdx.y, tid = threadIdx.x;
  const float4* xb = (const float4*)(xt + b * 9216);
  const float4* fr = (const float4*)(fs + ch * 9216);
  float s = 0.f;
#pragma unroll 3
  for (int g = tid; g < 2304; g += 256) {
    const float4 a = xb[g], d = fr[g];
    s += a.x * d.x + a.y * d.y + a.z * d.z + a.w * d.w;
  }
  s = wave_reduce(s);
  __shared__ float red[4];
  if ((tid & 63) == 0) red[tid >> 6] = s;
  __syncthreads();
  if (tid == 0) c[b * 121 + ch] = red[0] + red[1] + red[2] + red[3];
}

// fallback (uncoalesced) k_c, used only if ws too small for x_t
__global__ void k_c(const float* __restrict__ x, const float* __restrict__ fs,
                    float* __restrict__ c) {
  const int ch = blockIdx.x, b = blockIdx.y, tid = threadIdx.x;
  const float* xb = x + b * 9216;
  const float* fr = fs + ch * 9216;
  float s = 0.f;
  for (int g = tid; g < 9216; g += 256) {
    s += xb[(g % 96) * 96 + (g / 96)] * fr[g];
  }
  s = wave_reduce(s);
  __shared__ float red[4];
  if ((tid & 63) == 0) red[tid >> 6] = s;
  __syncthreads();
  if (tid == 0) c[b * 121 + ch] = red[0] + red[1] + red[2] + red[3];
}

__global__ void k_psi1(const float* __restrict__ Yk1, const float* __restrict__ w1,
                       float* __restrict__ psi1) {
  const int j = blockIdx.x, i = threadIdx.x;
  __shared__ float wsm[24];
  if (i < 24) wsm[i] = w1[j * 24 + i];
  __syncthreads();
  if (i < 121) {
    float s = 0.f;
#pragma unroll
    for (int n = 0; n < 24; ++n) s += Yk1[n * 121 + i] * wsm[n];
    psi1[j * 121 + i] = s * RS24;
  }
}

__global__ void k_h(const float* __restrict__ c, const float* __restrict__ psi1,
                    u16* __restrict__ hb) {
  const int j = blockIdx.x, b = blockIdx.y, tid = threadIdx.x;
  __shared__ float cs[121], ps[121];
  if (tid < 121) { cs[tid] = c[b * 121 + tid]; ps[tid] = psi1[j * 121 + tid]; }
  __syncthreads();
  for (int idx = tid; idx < K1P; idx += 256) {
    u16 v = 0;
    if (idx < NC1) {
      int off = 0, l = 0, k = 1;
      while (idx >= off + k * k) { off += k * k; ++l; k += 2; }
      const int r = idx - off, n = r / k, m = r % k;
      v = f2bf(cs[l * l + m] * ps[l * l + n]);
    }
    hb[(size_t)(b * F1_ + j) * K1P + idx] = v;
  }
}

// ------------------------- bf16 convert kernels ----------------------------

__global__ void k_cvt1(const float* __restrict__ in, uint32* __restrict__ out) {
  const int total = 32000 * 896;
  for (int id = blockIdx.x * 256 + threadIdx.x; id < total; id += gridDim.x * 256) {
    const int r = id / 896, c2 = id % 896, cc = c2 * 2;
    const float* p = in + (size_t)r * NC1 + cc;
    const float lo = (cc < NC1) ? p[0] : 0.f;
    const float hi = (cc + 1 < NC1) ? p[1] : 0.f;
    out[id] = pack_bf16(lo, hi);
  }
}

__global__ void k_cvt2(const float* __restrict__ in, uint32* __restrict__ out) {
  const int total = 286 * 16000;
  for (int id = blockIdx.x * 256 + threadIdx.x; id < total; id += gridDim.x * 256) {
    out[id] = pack_bf16(in[2 * id], in[2 * id + 1]);
  }
}

__global__ void k_cvt3(const float* __restrict__ in, uint32* __restrict__ out) {
  const int total = 6912 * 144;
  for (int id = blockIdx.x * 256 + threadIdx.x; id < total; id += gridDim.x * 256) {
    const int r = id / 144, c2 = id % 144, cc = c2 * 2;
    const float* p = in + (size_t)r * NC2 + cc;
    const float lo = (cc < NC2) ? p[0] : 0.f;
    const float hi = (cc + 1 < NC2) ? p[1] : 0.f;
    out[id] = pack_bf16(lo, hi);
  }
}

// ------------------- GEMM1: triple-buffered MFMA ---------------------------
// g[m,n] = bf16( sqrt(2)*relu( sum_k hb[m,k] * D1bf[n,k] ) )
// M=640, N=32000, K=1792. Tile 128x128, BK=32, 56 K-iters.
// 3 LDS buffer pairs (distinct objects -> no alias-forced waitcnt), one
// barrier per iter, vmcnt(4): the 4 loads issued last iter stay in flight.

__launch_bounds__(256)
__global__ void k_gemm1_v4(const u16* __restrict__ A, const u16* __restrict__ B,
                           u16* __restrict__ C) {
  __shared__ __align__(16) u16 As0[128 * 32], As1[128 * 32], As2[128 * 32];
  __shared__ __align__(16) u16 Bs0[128 * 32], Bs1[128 * 32], Bs2[128 * 32];
  const int bid = blockIdx.x;                // 0..1249
  const int gg = bid / 40, loc = bid % 40;
  int nt, mt;
  if (gg < 31) { nt = gg * 8 + (loc & 7); mt = loc >> 3; }
  else         { nt = 248 + (loc & 1);   mt = loc >> 1; }
  const int m0 = mt * 128, n0 = nt * 128;
  const int tid = threadIdx.x;
  const int lane = tid & 63, w = tid >> 6;
  const int wm = w >> 1, wn = w & 1;
  const int q = lane >> 4, r16 = lane & 15;

  const u16* ag = A + (size_t)(m0 + (tid >> 2)) * K1P + (tid & 3) * 8;
  const u16* bg = B + (size_t)(n0 + (tid >> 2)) * K1P + (tid & 3) * 8;

#define G1_ISSUE(kk, Asb, Bsb)                                                   \
  {                                                                              \
    _Pragma("unroll")                                                            \
    for (int i = 0; i < 2; ++i) {                                                \
      __builtin_amdgcn_global_load_lds(AS1(ag + (kk) * 32 + (size_t)i * 64 * K1P), \
          AS3((char*)(Asb) + i * 4096 + w * 1024), 16, 0, 0);                    \
      __builtin_amdgcn_global_load_lds(AS1(bg + (kk) * 32 + (size_t)i * 64 * K1P), \
          AS3((char*)(Bsb) + i * 4096 + w * 1024), 16, 0, 0);                    \
    }                                                                            \
  }

#define G1_COMPUTE(Asb, Bsb)                                                     \
  {                                                                              \
    short8 af[4], bq[4];                                                         \
    _Pragma("unroll")                                                            \
    for (int mb = 0; mb < 4; ++mb)                                               \
      af[mb] = *(const short8*)&(Asb)[(wm * 64 + mb * 16 + r16) * 32 + q * 8];   \
    _Pragma("unroll")                                                            \
    for (int nb = 0; nb < 4; ++nb)                                               \
      bq[nb] = *(const short8*)&(Bsb)[(wn * 64 + nb * 16 + r16) * 32 + q * 8];   \
    _Pragma("unroll")                                                            \
    for (int mb = 0; mb < 4; ++mb)                                               \
      _Pragma("unroll")                                                          \
      for (int nb = 0; nb < 4; ++nb)                                             \
        acc[mb][nb] = __builtin_amdgcn_mfma_f32_16x16x32_bf16(af[mb], bq[nb],    \
                                                              acc[mb][nb], 0, 0, 0); \
  }

#define G1_STAGE(kk, AsR, BsR, AsI, BsI)        \
  {                                             \
    __builtin_amdgcn_s_waitcnt(WAITCNT_VM4);    \
    __builtin_amdgcn_s_barrier();               \
    asm volatile("" ::: "memory");              \
    if ((kk) + 2 < 56) G1_ISSUE((kk) + 2, AsI, BsI) \
    G1_COMPUTE(AsR, BsR)                        \
  }

  f32x4 acc[4][4] = {};
  G1_ISSUE(0, As0, Bs0)
  G1_ISSUE(1, As1, Bs1)
  for (int k = 0; k < 54; k += 3) {
    G1_STAGE(k,     As0, Bs0, As2, Bs2)
    G1_STAGE(k + 1, As1, Bs1, As0, Bs0)
    G1_STAGE(k + 2, As2, Bs2, As1, Bs1)
  }
  G1_STAGE(54, As0, Bs0, As2, Bs2)
  G1_STAGE(55, As1, Bs1, As0, Bs0)

#pragma unroll
  for (int mb = 0; mb < 4; ++mb) {
#pragma unroll
    for (int nb = 0; nb < 4; ++nb) {
      const int col = n0 + wn * 64 + nb * 16 + r16;
#pragma unroll
      for (int r = 0; r < 4; ++r) {
        const int row = m0 + wm * 64 + mb * 16 + q * 4 + r;
        float v = acc[mb][nb][r];
        v = (v > 0.f) ? v * SQRT2_ : 0.f;
        C[(size_t)row * NG1 + col] = f2bf(v);
      }
    }
  }
#undef G1_ISSUE
#undef G1_COMPUTE
#undef G1_STAGE
}

// ------------------- GEMM2: triple-buffered, split-K=20 --------------------
// h2[m,n] += sum_k g[m,k] * F1bf[n,k]; M=640, N=286, K=32000 -> 20x1600.
__launch_bounds__(256)
__global__ void k_gemm2_v4(const u16* __restrict__ A, const u16* __restrict__ B,
                           float* __restrict__ C) {
  __shared__ __align__(16) u16 As0[128 * 32], As1[128 * 32], As2[128 * 32];
  __shared__ __align__(16) u16 Bs0[128 * 32], Bs1[128 * 32], Bs2[128 * 32];
  const int m0 = blockIdx.x * 128, n0 = blockIdx.y * 128;
  const int ks = blockIdx.z * 1600;
  const int tid = threadIdx.x;
  const int lane = tid & 63, w = tid >> 6;
  const int wm = w >> 1, wn = w & 1;
  const int q = lane >> 4, r16 = lane & 15;

  const u16* ag = A + (size_t)(m0 + (tid >> 2)) * NG1 + ks + (tid & 3) * 8;
  int rb0 = n0 + (tid >> 2);        if (rb0 > 285) rb0 = 285;
  int rb1 = n0 + (tid >> 2) + 64;   if (rb1 > 285) rb1 = 285;
  const u16* bg0 = B + (size_t)rb0 * NG1 + ks + (tid & 3) * 8;
  const u16* bg1 = B + (size_t)rb1 * NG1 + ks + (tid & 3) * 8;

#define G2_ISSUE(kk, Asb, Bsb)                                                   \
  {                                                                              \
    _Pragma("unroll")                                                            \
    for (int i = 0; i < 2; ++i)                                                  \
      __builtin_amdgcn_global_load_lds(AS1(ag + (kk) * 32 + (size_t)i * 64 * NG1), \
          AS3((char*)(Asb) + i * 4096 + w * 1024), 16, 0, 0);                    \
    __builtin_amdgcn_global_load_lds(AS1(bg0 + (kk) * 32),                       \
        AS3((char*)(Bsb) + w * 1024), 16, 0, 0);                                 \
    __builtin_amdgcn_global_load_lds(AS1(bg1 + (kk) * 32),                       \
        AS3((char*)(Bsb) + 4096 + w * 1024), 16, 0, 0);                          \
  }

#define G2_COMPUTE(Asb, Bsb)                                                     \
  {                                                                              \
    short8 af[4], bq[4];                                                         \
    _Pragma("unroll")                                                            \
    for (int mb = 0; mb < 4; ++mb)                                               \
      af[mb] = *(const short8*)&(Asb)[(wm * 64 + mb * 16 + r16) * 32 + q * 8];   \
    _Pragma("unroll")                                                            \
    for (int nb = 0; nb < 4; ++nb)                                               \
      bq[nb] = *(const short8*)&(Bsb)[(wn * 64 + nb * 16 + r16) * 32 + q * 8];   \
    _Pragma("unroll")                                                            \
    for (int mb = 0; mb < 4; ++mb)                                               \
      _Pragma("unroll")                                                          \
      for (int nb = 0; nb < 4; ++nb)                                             \
        acc[mb][nb] = __builtin_amdgcn_mfma_f32_16x16x32_bf16(af[mb], bq[nb],    \
                                                              acc[mb][nb], 0, 0, 0); \
  }

#define G2_STAGE(kk, AsR, BsR, AsI, BsI)        \
  {                                             \
    __builtin_amdgcn_s_waitcnt(WAITCNT_VM4);    \
    __builtin_amdgcn_s_barrier();               \
    asm volatile("" ::: "memory");              \
    if ((kk) + 2 < 50) G2_ISSUE((kk) + 2, AsI, BsI) \
    G2_COMPUTE(AsR, BsR)                        \
  }

  f32x4 acc[4][4] = {};
  G2_ISSUE(0, As0, Bs0)
  G2_ISSUE(1, As1, Bs1)
  for (int k = 0; k < 48; k += 3) {
    G2_STAGE(k,     As0, Bs0, As2, Bs2)
    G2_STAGE(k + 1, As1, Bs1, As0, Bs0)
    G2_STAGE(k + 2, As2, Bs2, As1, Bs1)
  }
  G2_STAGE(48, As0, Bs0, As2, Bs2)
  G2_STAGE(49, As1, Bs1, As0, Bs0)

#pragma unroll
  for (int mb = 0; mb < 4; ++mb) {
#pragma unroll
    for (int nb = 0; nb < 4; ++nb) {
      const int col = n0 + wn * 64 + nb * 16 + r16;
      if (col < NC2) {
#pragma unroll
        for (int r = 0; r < 4; ++r) {
          const int row = m0 + wm * 64 + mb * 16 + q * 4 + r;
          atomicAdd(&C[(size_t)row * NC2 + col], acc[mb][nb][r]);
        }
      }
    }
  }
#undef G2_ISSUE
#undef G2_COMPUTE
#undef G2_STAGE
}

// GEMM3 fused epilogue: out[m] += sqrt(2)*sum_n relu(sum_k h3b[m,k]*D2bf[n,k])*F2_from[n]
__launch_bounds__(256)
__global__ void k_gemm3_v3(const u16* __restrict__ A, const u16* __restrict__ B,
                           const float* __restrict__ wv, float* __restrict__ out) {
  __shared__ __align__(16) u16 As[128 * 32];
  __shared__ __align__(16) u16 Bs[128 * 32];
  __shared__ float red[128][33];
  const int m0 = blockIdx.x * 128, n0 = blockIdx.y * 128;
  const int tid = threadIdx.x;
  const int lane = tid & 63, w = tid >> 6;
  const int wm = w >> 1, wn = w & 1;
  const int q = lane >> 4, r16 = lane & 15;

  f32x4 acc[4][4] = {};
  const u16* ag = A + (size_t)(m0 + (tid >> 2)) * K2P + (tid & 3) * 8;
  const u16* bg = B + (size_t)(n0 + (tid >> 2)) * K2P + (tid & 3) * 8;

  for (int k0 = 0; k0 < K2P; k0 += 32) {
#pragma unroll
    for (int i = 0; i < 2; ++i) {
      __builtin_amdgcn_global_load_lds(AS1(ag + k0 + (size_t)i * 64 * K2P),
                                       AS3((char*)As + i * 4096 + w * 1024), 16, 0, 0);
      __builtin_amdgcn_global_load_lds(AS1(bg + k0 + (size_t)i * 64 * K2P),
                                       AS3((char*)Bs + i * 4096 + w * 1024), 16, 0, 0);
    }
    __syncthreads();
    short8 af[4], bq[4];
#pragma unroll
    for (int mb = 0; mb < 4; ++mb)
      af[mb] = *(const short8*)&As[(wm * 64 + mb * 16 + r16) * 32 + q * 8];
#pragma unroll
    for (int nb = 0; nb < 4; ++nb)
      bq[nb] = *(const short8*)&Bs[(wn * 64 + nb * 16 + r16) * 32 + q * 8];
#pragma unroll
    for (int mb = 0; mb < 4; ++mb)
#pragma unroll
      for (int nb = 0; nb < 4; ++nb)
        acc[mb][nb] = __builtin_amdgcn_mfma_f32_16x16x32_bf16(af[mb], bq[nb], acc[mb][nb], 0, 0, 0);
    __syncthreads();
  }
  float wvv[4];
#pragma unroll
  for (int nb = 0; nb < 4; ++nb) wvv[nb] = wv[n0 + wn * 64 + nb * 16 + r16];
#pragma unroll
  for (int mb = 0; mb < 4; ++mb) {
#pragma unroll
    for (int r = 0; r < 4; ++r) {
      const int rowl = wm * 64 + mb * 16 + q * 4 + r;
      float t = 0.f;
#pragma unroll
      for (int nb = 0; nb < 4; ++nb) {
        float v = acc[mb][nb][r];
        v = (v > 0.f) ? v : 0.f;
        t += v * wvv[nb];
      }
      red[rowl][wn * 16 + r16] = t;
    }
  }
  __syncthreads();
  if (tid < 128) {
    float s = 0.f;
#pragma unroll
    for (int cc = 0; cc < 32; ++cc) s += red[tid][cc];
    atomicAdd(&out[m0 + tid], s * SQRT2_);
  }
}

// ------------------- fallback GEMM1/GEMM2 (on-the-fly cvt) -----------------

__launch_bounds__(256)
__global__ void k_gemm1_mfma(const u16* __restrict__ A, const float* __restrict__ Bf,
                             u16* __restrict__ C) {
  __shared__ __align__(16) u16 As[128 * 32];
  __shared__ __align__(16) u16 Bs[128 * 32];
  const int tid = threadIdx.x;
  const int lane = tid & 63, w = tid >> 6;
  const int wm = w >> 1, wn = w & 1;
  const int q = lane >> 4, r16 = lane & 15;
  const int m0 = blockIdx.x * 128, n0 = blockIdx.y * 128;

  f32x4 acc[4][4] = {};
  const u16* ag = A + (size_t)(m0 + (tid >> 2)) * K1P + (tid & 3) * 8;

  for (int k0 = 0; k0 < K1P; k0 += 32) {
#pragma unroll
    for (int i = 0; i < 2; ++i) {
      __builtin_amdgcn_global_load_lds(AS1(ag + k0 + (size_t)i * 64 * K1P),
                                       AS3((char*)As + i * 4096 + w * 1024), 16, 0, 0);
    }
#pragma unroll
    for (int i = 0; i < 8; ++i) {
      const int p = i * 256 + tid;
      const int row = p >> 4, c2 = (p & 15) * 2;
      const int kk = k0 + c2;
      const float* bp = Bf + (size_t)(n0 + row) * NC1 + kk;
      const float lo = (kk < NC1) ? bp[0] : 0.f;
      const float hi = (kk + 1 < NC1) ? bp[1] : 0.f;
      ((uint32*)Bs)[row * 16 + (p & 15)] = pack_bf16(lo, hi);
    }
    __syncthreads();
    short8 af[4], bq[4];
#pragma unroll
    for (int mb = 0; mb < 4; ++mb)
      af[mb] = *(const short8*)&As[(wm * 64 + mb * 16 + r16) * 32 + q * 8];
#pragma unroll
    for (int nb = 0; nb < 4; ++nb)
      bq[nb] = *(const short8*)&Bs[(wn * 64 + nb * 16 + r16) * 32 + q * 8];
#pragma unroll
    for (int mb = 0; mb < 4; ++mb)
#pragma unroll
      for (int nb = 0; nb < 4; ++nb)
        acc[mb][nb] = __builtin_amdgcn_mfma_f32_16x16x32_bf16(af[mb], bq[nb], acc[mb][nb], 0, 0, 0);
    __syncthreads();
  }
#pragma unroll
  for (int mb = 0; mb < 4; ++mb) {
#pragma unroll
    for (int nb = 0; nb < 4; ++nb) {
      const int col = n0 + wn * 64 + nb * 16 + r16;
#pragma unroll
      for (int r = 0; r < 4; ++r) {
        const int row = m0 + wm * 64 + mb * 16 + q * 4 + r;
        float v = acc[mb][nb][r];
        v = (v > 0.f) ? v * SQRT2_ : 0.f;
        C[(size_t)row * NG1 + col] = f2bf(v);
      }
    }
  }
}

__launch_bounds__(256)
__global__ void k_gemm2_mfma(const u16* __restrict__ A, const float* __restrict__ Bf,
                             float* __restrict__ C) {
  __shared__ __align__(16) u16 As[128 * 32];
  __shared__ __align__(16) u16 Bs[128 * 32];
  const int tid = threadIdx.x;
  const int lane = tid & 63, w = tid >> 6;
  const int wm = w >> 1, wn = w & 1;
  const int q = lane >> 4, r16 = lane & 15;
  const int m0 = blockIdx.x * 128, n0 = blockIdx.y * 128;
  const int ks = blockIdx.z * 1600;

  f32x4 acc[4][4] = {};
  const u16* ag = A + (size_t)(m0 + (tid >> 2)) * NG1 + ks + (tid & 3) * 8;

  for (int kt = 0; kt < 1600; kt += 32) {
#pragma unroll
    for (int i = 0; i < 2; ++i) {
      __builtin_amdgcn_global_load_lds(AS1(ag + kt + (size_t)i * 64 * NG1),
                                       AS3((char*)As + i * 4096 + w * 1024), 16, 0, 0);
    }
#pragma unroll
    for (int i = 0; i < 4; ++i) {
      const int idx = i * 256 + tid;
      const int row = idx >> 3, c4 = (idx & 7) * 4;
      const int n = n0 + row;
      float4 v = make_float4(0.f, 0.f, 0.f, 0.f);
      if (n < NC2) v = *(const float4*)(Bf + (size_t)n * NG1 + ks + kt + c4);
      ((uint32*)Bs)[row * 16 + (idx & 7) * 2]     = pack_bf16(v.x, v.y);
      ((uint32*)Bs)[row * 16 + (idx & 7) * 2 + 1] = pack_bf16(v.z, v.w);
    }
    __syncthreads();
    short8 af[4], bq[4];
#pragma unroll
    for (int mb = 0; mb < 4; ++mb)
      af[mb] = *(const short8*)&As[(wm * 64 + mb * 16 + r16) * 32 + q * 8];
#pragma unroll
    for (int nb = 0; nb < 4; ++nb)
      bq[nb] = *(const short8*)&Bs[(wn * 64 + nb * 16 + r16) * 32 + q * 8];
#pragma unroll
    for (int mb = 0; mb < 4; ++mb)
#pragma unroll
      for (int nb = 0; nb < 4; ++nb)
        acc[mb][nb] = __builtin_amdgcn_mfma_f32_16x16x32_bf16(af[mb], bq[nb], acc[mb][nb], 0, 0, 0);
    __syncthreads();
  }
#pragma unroll
  for (int mb = 0; mb < 4; ++mb) {
#pragma unroll
    for (int nb = 0; nb < 4; ++nb) {
      const int col = n0 + wn * 64 + nb * 16 + r16;
      if (col < NC2) {
#pragma unroll
        for (int r = 0; r < 4; ++r) {
          const int row = m0 + wm * 64 + mb * 16 + q * 4 + r;
          atomicAdd(&C[(size_t)row * NC2 + col], acc[mb][nb][r]);
        }
      }
    }
  }
}

// ------------------------- mid/tail kernels --------------------------------

__global__ void k_psi2(const float* __restrict__ Dk2, const float* __restrict__ w2,
                       float* __restrict__ psi2) {
  const int blk = blockIdx.x, tid = threadIdx.x;   // blk = i*40+j
  __shared__ float w2s[168];
  if (tid < 168) w2s[tid] = w2[blk * 168 + tid];
  __syncthreads();
  for (int cc = tid; cc < NC2; cc += 256) {
    float s = 0.f;
    for (int n = 0; n < 168; ++n) s += Dk2[n * NC2 + cc] * w2s[n];
    psi2[blk * NC2 + cc] = s * RS168;
  }
}

__global__ void k_step7(const float* __restrict__ h2, const float* __restrict__ psi2,
                        u16* __restrict__ h3b) {
  const int j = blockIdx.x, b = blockIdx.y, tid = threadIdx.x;
  __shared__ float sh[20 * 286];
  __shared__ float sp[20 * 286];
  for (int e = tid; e < 20 * 286; e += 256) {
    const int i = e / 286, cc = e % 286;
    sh[e] = h2[(b * F1_ + i) * NC2 + cc];
    sp[e] = psi2[(i * F2_ + j) * NC2 + cc];
  }
  __syncthreads();
  for (int cidx = tid; cidx < K2P; cidx += 256) {
    u16 ov = 0;
    if (cidx < NC2) {
      int off = 0, l = 0, k = 1;
      while (cidx >= off + k * k) { off += k * k; ++l; k += 2; }
      const int r = cidx - off, v = r / k, m = r % k;
      float acc = 0.f;
      for (int i = 0; i < 20; ++i) {
        const float* hbp = &sh[i * 286 + off];
        const float* pb = &sp[i * 286 + off];
        for (int u = 0; u < k; ++u) acc += hbp[u * k + m] * pb[u * k + v];
      }
      ov = f2bf(acc * rsqrtf(20.f * (float)k));
    }
    h3b[(size_t)(b * F2_ + j) * K2P + cidx] = ov;
  }
}

// ------------------------------- launcher ----------------------------------

extern "C" void kernel_launch(void* const* d_in, const int* in_sizes, int n_in,
                              void* d_out, int out_size, void* d_ws, size_t ws_size,
                              hipStream_t stream) {
  const float* x       = (const float*)d_in[0];
  const float* w1      = (const float*)d_in[1];
  const float* w2      = (const float*)d_in[2];
  const float* Yk1     = (const float*)d_in[3];
  const float* Dk2     = (const float*)d_in[4];
  const float* from_s2 = (const float*)d_in[5];
  const float* D1_to   = (const float*)d_in[6];
  const float* F1_from = (const float*)d_in[7];
  const float* D2_to   = (const float*)d_in[8];
  const float* F2_from = (const float*)d_in[9];
  float* out = (float*)d_out;

  float* ws = (float*)d_ws;
  float* c    = ws + 0;            //   3,872
  float* psi1 = ws + 3872;         //   2,420
  float* h2   = ws + 6292;         // 183,040
  float* psi2 = ws + 189332;       // 228,800
  u16*   h3b  = (u16*)(ws + 418132);      // 1280*288 u16  = 184,320 f
  u16*   hb   = (u16*)(ws + 602452);      // 640*1792 u16  = 573,440 f
  u16*   g    = (u16*)(ws + 1175892);     // 640*32000 u16 = 10,240,000 f
  u16*   D2bf = (u16*)(ws + 11415892);    // 6912*288 u16  = 995,328 f
  u16*   F1bf = (u16*)(ws + 12411220);    // 286*32000 u16 = 4,576,000 f
  u16*   D1bf = (u16*)(ws + 16987220);    // 32000*1792 u16= 28,672,000 f
  float* x_t  = ws + 45659220;            // 32*9216       = 294,912 f
  const size_t BIG_NEED = (size_t)45659220 * 4;   // ~182.6 MB (proven OK R3)
  const size_t XT_NEED  = (size_t)45954132 * 4;   // +x_t
  const bool big   = ws_size >= BIG_NEED;
  const bool useXT = ws_size >= XT_NEED;

  if (useXT) {
    k_xt<<<dim3(3, 3, 32), 256, 0, stream>>>(x, x_t);
    k_c2<<<dim3(121, 32),  256, 0, stream>>>(x_t, from_s2, c);
  } else {
    k_c <<<dim3(121, 32),  256, 0, stream>>>(x, from_s2, c);
  }
  k_psi1<<<dim3(20),      128, 0, stream>>>(Yk1, w1, psi1);
  k_h   <<<dim3(20, 32),  256, 0, stream>>>(c, psi1, hb);
  k_cvt3<<<dim3(1024),    256, 0, stream>>>(D2_to, (uint32*)D2bf);

  if (big) {
    k_cvt1<<<dim3(8192), 256, 0, stream>>>(D1_to, (uint32*)D1bf);
    k_cvt2<<<dim3(4096), 256, 0, stream>>>(F1_from, (uint32*)F1bf);
    k_gemm1_v4<<<dim3(1250), 256, 0, stream>>>(hb, D1bf, g);
    hipMemsetAsync(h2, 0, (size_t)640 * 286 * sizeof(float), stream);
    k_gemm2_v4<<<dim3(5, 3, 20), 256, 0, stream>>>(g, F1bf, h2);
  } else {
    k_gemm1_mfma<<<dim3(5, 250), 256, 0, stream>>>(hb, D1_to, g);
    hipMemsetAsync(h2, 0, (size_t)640 * 286 * sizeof(float), stream);
    k_gemm2_mfma<<<dim3(5, 3, 20), 256, 0, stream>>>(g, F1_from, h2);
  }

  k_psi2 <<<dim3(800),    256, 0, stream>>>(Dk2, w2, psi2);
  k_step7<<<dim3(40, 32), 256, 0, stream>>>(h2, psi2, h3b);

  hipMemsetAsync(out, 0, (size_t)1280 * sizeof(float), stream);
  k_gemm3_v3<<<dim3(10, 54), 256, 0, stream>>>(h3b, D2bf, F2_from, out);
}